// Round 2
// baseline (792.173 us; speedup 1.0000x reference)
//
#include <hip/hip_runtime.h>
#include <hip/hip_bf16.h>

#define B_ 8
#define N_ 2048
#define D_ 256

using bf16 = __hip_bfloat16;
typedef short v8s __attribute__((ext_vector_type(8)));
typedef float v4f __attribute__((ext_vector_type(4)));

__device__ __forceinline__ v4f mfma16(v8s a, v8s b, v4f c) {
  return __builtin_amdgcn_mfma_f32_16x16x32_bf16(a, b, c, 0, 0, 0);
}
__device__ __forceinline__ v8s ldb8(const bf16* p) {
  return *reinterpret_cast<const v8s*>(p);
}
__device__ __forceinline__ unsigned short f2bu(float f) {
  bf16 b = __float2bfloat16(f);
  return *reinterpret_cast<unsigned short*>(&b);
}
__device__ __forceinline__ float fsigmoid(float x) { return 1.0f / (1.0f + __expf(-x)); }
__device__ __forceinline__ float ftanh(float x) {
  float ax = fabsf(x);
  float t = __expf(-2.0f * ax);
  float r = (1.0f - t) / (1.0f + t);
  return copysignf(r, x);
}

// ---------------- K0: f32 -> bf16 cast (vector x4) ----------------
__global__ __launch_bounds__(256) void k_cvt(const float* __restrict__ src,
                                             bf16* __restrict__ dst, int n4) {
  int i = blockIdx.x * 256 + threadIdx.x;
  if (i >= n4) return;
  float4 v = reinterpret_cast<const float4*>(src)[i];
  ushort4 o;
  o.x = f2bu(v.x); o.y = f2bu(v.y); o.z = f2bu(v.z); o.w = f2bu(v.w);
  reinterpret_cast<ushort4*>(dst)[i] = o;
}

// ---------------- K1: reciprocal row norms of x_topic (f32 in) ----------------
__global__ __launch_bounds__(256) void k_rnorm(const float* __restrict__ xt,
                                               float* __restrict__ rnorm) {
  int wave = threadIdx.x >> 6, lane = threadIdx.x & 63;
  int row = blockIdx.x * 4 + wave;                 // 16384 rows
  const float4* p4 = (const float4*)(xt + (size_t)row * D_);
  float4 v = p4[lane];
  float s = v.x * v.x + v.y * v.y + v.z * v.z + v.w * v.w;
  for (int off = 32; off > 0; off >>= 1) s += __shfl_down(s, off);
  if (lane == 0) rnorm[row] = 1.0f / fmaxf(sqrtf(s), 1e-8f);
}

// ---------------- K2: W[d][h] (f32) -> Wt[h][d] (bf16, K-major) ----------------
__global__ __launch_bounds__(256) void k_twt(const float* __restrict__ W,
                                             bf16* __restrict__ Wt) {
  int idx = blockIdx.x * 256 + threadIdx.x;        // 65536
  int d = idx >> 8, h = idx & 255;
  Wt[h * 256 + d] = __float2bfloat16(W[idx]);
}

// ---------------- K3: WhT[b][h][m] = sum_d Wt[h][d] * x16[b][m][d] ----------------
__global__ __launch_bounds__(256) void k_wht(const bf16* __restrict__ x,
                                             const bf16* __restrict__ Wt,
                                             bf16* __restrict__ WhT) {
  int wid = blockIdx.x * 4 + (threadIdx.x >> 6);   // 4096 waves
  int lane = threadIdx.x & 63, lr = lane & 15, quad = lane >> 4;
  int b = wid >> 9;
  int rem = wid & 511;
  int h0 = (rem >> 5) << 4;                        // 16 h-tiles
  int m0 = (rem & 31) << 6;                        // 32 m-strips of 64

  v8s a[8];
  const bf16* arow = Wt + (size_t)(h0 + lr) * D_ + quad * 8;
#pragma unroll
  for (int ks = 0; ks < 8; ks++) a[ks] = ldb8(arow + ks * 32);

  const bf16* xb = x + (size_t)b * N_ * D_;
#pragma unroll
  for (int mt = 0; mt < 4; mt++) {
    v4f acc = {0.f, 0.f, 0.f, 0.f};
    const bf16* brow = xb + (size_t)(m0 + mt * 16 + lr) * D_ + quad * 8;
#pragma unroll
    for (int ks = 0; ks < 8; ks++) acc = mfma16(a[ks], ldb8(brow + ks * 32), acc);
    // C: row = h0+quad*4+r, col = m0+mt*16+lr
    bf16* o = WhT + ((size_t)b * D_ + h0 + quad * 4) * N_ + m0 + mt * 16 + lr;
#pragma unroll
    for (int r = 0; r < 4; r++) o[(size_t)r * N_] = __float2bfloat16(acc[r]);
  }
}

// ---------------- K4: fused masked-cosine softmax attention ----------------
// per-wave: 16 Q-rows, m-loop in tiles of 32; p = mask ? exp(cos) : 0 (cos in
// [-1,1] so no running max needed); O += P @ WhT; normalize by row-sum at end.
__global__ __launch_bounds__(256) void k_attn(const bf16* __restrict__ xt,
                                              const int* __restrict__ adj,
                                              const bf16* __restrict__ WhT,
                                              const float* __restrict__ rnorm,
                                              bf16* __restrict__ gout) {
  __shared__ __align__(16) bf16 pbuf[4][16][32];   // per-wave P staging (C->A layout)
  int w = threadIdx.x >> 6;
  int lane = threadIdx.x & 63, lr = lane & 15, quad = lane >> 4;
  int wid = blockIdx.x * 4 + w;                    // 1024 waves
  int b = wid >> 7;
  int n0 = (wid & 127) << 4;

  const bf16* xtb = xt + (size_t)b * N_ * D_;
  const bf16* whb = WhT + (size_t)b * D_ * N_;
  const float* rnb = rnorm + b * N_;
  const int* adjb = adj + (size_t)b * N_ * N_;

  // Q fragments held in registers for the whole m-loop (A-layout)
  v8s q[8];
  const bf16* qrow = xtb + (size_t)(n0 + lr) * D_ + quad * 8;
#pragma unroll
  for (int ks = 0; ks < 8; ks++) q[ks] = ldb8(qrow + ks * 32);

  float rn[4];
#pragma unroll
  for (int r = 0; r < 4; r++) rn[r] = rnorm[b * N_ + n0 + quad * 4 + r];

  v4f o[16];
#pragma unroll
  for (int t = 0; t < 16; t++) o[t] = (v4f){0.f, 0.f, 0.f, 0.f};
  float lsum[4] = {0.f, 0.f, 0.f, 0.f};

#pragma unroll 1
  for (int mi = 0; mi < 64; mi++) {
    int m0 = mi * 32;
    // S = Q . K^T for two 16-col tiles
    v4f s0 = {0.f, 0.f, 0.f, 0.f}, s1 = {0.f, 0.f, 0.f, 0.f};
    const bf16* k0r = xtb + (size_t)(m0 + lr) * D_ + quad * 8;
    const bf16* k1r = k0r + 16 * D_;
#pragma unroll
    for (int ks = 0; ks < 8; ks++) {
      s0 = mfma16(q[ks], ldb8(k0r + ks * 32), s0);
      s1 = mfma16(q[ks], ldb8(k1r + ks * 32), s1);
    }
    float rm0 = rnb[m0 + lr];
    float rm1 = rnb[m0 + 16 + lr];
    const int* arow = adjb + (size_t)(n0 + quad * 4) * N_ + m0 + lr;
#pragma unroll
    for (int r = 0; r < 4; r++) {
      int mk0 = arow[(size_t)r * N_];
      int mk1 = arow[(size_t)r * N_ + 16];
      float p0 = (mk0 > 0) ? __expf(s0[r] * rn[r] * rm0) : 0.f;
      float p1 = (mk1 > 0) ? __expf(s1[r] * rn[r] * rm1) : 0.f;
      lsum[r] += p0 + p1;
      pbuf[w][quad * 4 + r][lr]      = __float2bfloat16(p0);
      pbuf[w][quad * 4 + r][lr + 16] = __float2bfloat16(p1);
    }
    // PV: O[16 n][256 h] += P(16x32) @ WhT(256h x 32m); A-frag from LDS
    v8s pa = *reinterpret_cast<const v8s*>(&pbuf[w][lr][quad * 8]);
#pragma unroll
    for (int ht = 0; ht < 16; ht++) {
      const bf16* wrow = whb + (size_t)(ht * 16 + lr) * N_ + m0 + quad * 8;
      o[ht] = mfma16(pa, ldb8(wrow), o[ht]);
    }
  }

  // reduce row sums across the 16 lanes of the quad, normalize + store (bf16)
#pragma unroll
  for (int r = 0; r < 4; r++) {
    float t = lsum[r];
    t += __shfl_xor(t, 1); t += __shfl_xor(t, 2);
    t += __shfl_xor(t, 4); t += __shfl_xor(t, 8);
    lsum[r] = 1.0f / t;
  }
  bf16* ob = gout + ((size_t)b * N_ + n0 + quad * 4) * D_ + lr;
#pragma unroll
  for (int r = 0; r < 4; r++) {
#pragma unroll
    for (int ht = 0; ht < 16; ht++) {
      ob[(size_t)r * D_ + ht * 16] = __float2bfloat16(o[ht][r] * lsum[r]);
    }
  }
}

// ---------------- K5: fused GRU cell (f32 out) ----------------
// wave = 64 rows x 16 cols; 6 GEMM accumulators (r,z,n for ih and hh), K=256
__global__ __launch_bounds__(256) void k_gru(const bf16* __restrict__ gout,
                                             const bf16* __restrict__ x16,
                                             const bf16* __restrict__ Wih,
                                             const bf16* __restrict__ Whh,
                                             const float* __restrict__ bih,
                                             const float* __restrict__ bhh,
                                             const float* __restrict__ x32,
                                             float* __restrict__ out) {
  int wid = blockIdx.x * 4 + (threadIdx.x >> 6);   // 4096 waves
  int lane = threadIdx.x & 63, lr = lane & 15, quad = lane >> 4;
  int rs = wid >> 4;                               // 256 row-strips of 64
  int col0 = (wid & 15) << 4;                      // 16 col-tiles
  int row0 = rs << 6;
  int col = col0 + lr;

  float bi[3], bh[3];
#pragma unroll
  for (int g = 0; g < 3; g++) {
    bi[g] = bih[g * 256 + col];
    bh[g] = bhh[g * 256 + col];
  }
  v4f aI[3][4], aH[3][4];
#pragma unroll
  for (int g = 0; g < 3; g++)
#pragma unroll
    for (int rt = 0; rt < 4; rt++) {
      aI[g][rt] = (v4f){0.f, 0.f, 0.f, 0.f};
      aH[g][rt] = (v4f){0.f, 0.f, 0.f, 0.f};
    }

#pragma unroll 2
  for (int ks = 0; ks < 8; ks++) {
    int k0 = ks * 32 + quad * 8;
    v8s wI[3], wH[3];
#pragma unroll
    for (int g = 0; g < 3; g++) {
      wI[g] = ldb8(Wih + (size_t)(g * 256 + col0 + lr) * 256 + k0);
      wH[g] = ldb8(Whh + (size_t)(g * 256 + col0 + lr) * 256 + k0);
    }
#pragma unroll
    for (int rt = 0; rt < 4; rt++) {
      v8s aG = ldb8(gout + (size_t)(row0 + rt * 16 + lr) * 256 + k0);
      v8s aX = ldb8(x16 + (size_t)(row0 + rt * 16 + lr) * 256 + k0);
#pragma unroll
      for (int g = 0; g < 3; g++) {
        aI[g][rt] = mfma16(aG, wI[g], aI[g][rt]);
        aH[g][rt] = mfma16(aX, wH[g], aH[g][rt]);
      }
    }
  }

#pragma unroll
  for (int rt = 0; rt < 4; rt++) {
    int rowb = row0 + rt * 16 + quad * 4;
#pragma unroll
    for (int r = 0; r < 4; r++) {
      float ir  = aI[0][rt][r] + bi[0];
      float iz  = aI[1][rt][r] + bi[1];
      float in_ = aI[2][rt][r] + bi[2];
      float hr  = aH[0][rt][r] + bh[0];
      float hz  = aH[1][rt][r] + bh[1];
      float hn  = aH[2][rt][r] + bh[2];
      float rg = fsigmoid(ir + hr);
      float zg = fsigmoid(iz + hz);
      float ng = ftanh(in_ + rg * hn);
      float hv = x32[(size_t)(rowb + r) * 256 + col];
      out[(size_t)(rowb + r) * 256 + col] = (1.0f - zg) * ng + zg * hv;
    }
  }
}

extern "C" void kernel_launch(void* const* d_in, const int* in_sizes, int n_in,
                              void* d_out, int out_size, void* d_ws, size_t ws_size,
                              hipStream_t stream) {
  const int*   adj = (const int*)d_in[0];
  const float* x   = (const float*)d_in[1];
  const float* xt  = (const float*)d_in[2];
  const float* W   = (const float*)d_in[3];
  const float* Wih = (const float*)d_in[4];
  const float* Whh = (const float*)d_in[5];
  const float* bih = (const float*)d_in[6];
  const float* bhh = (const float*)d_in[7];
  float* out = (float*)d_out;

  char* ws = (char*)d_ws;
  bf16*  xb16   = (bf16*)(ws);                     //  8 MiB  (B*N*D)
  bf16*  xtb16  = (bf16*)(ws + (8u << 20));        //  8 MiB
  bf16*  gob    = (bf16*)(ws + (16u << 20));       //  8 MiB
  bf16*  WhT    = (bf16*)(ws + (24u << 20));       //  8 MiB
  bf16*  Wt     = (bf16*)(ws + (32u << 20));                 // 128 KiB
  bf16*  Wih16  = (bf16*)(ws + (32u << 20) + 131072);        // 384 KiB
  bf16*  Whh16  = (bf16*)(ws + (32u << 20) + 131072 + 393216);
  float* rnorm  = (float*)(ws + (32u << 20) + 131072 + 2 * 393216);

  const int nBND4 = B_ * N_ * D_ / 4;              // 1048576
  k_cvt<<<nBND4 / 256, 256, 0, stream>>>(x,  xb16,  nBND4);
  k_cvt<<<nBND4 / 256, 256, 0, stream>>>(xt, xtb16, nBND4);
  k_cvt<<<192, 256, 0, stream>>>(Wih, Wih16, 49152);
  k_cvt<<<192, 256, 0, stream>>>(Whh, Whh16, 49152);
  k_twt<<<256, 256, 0, stream>>>(W, Wt);
  k_rnorm<<<4096, 256, 0, stream>>>(xt, rnorm);
  k_wht<<<1024, 256, 0, stream>>>(xb16, Wt, WhT);
  k_attn<<<256, 256, 0, stream>>>(xtb16, adj, WhT, rnorm, gob);
  k_gru<<<1024, 256, 0, stream>>>(gob, xb16, Wih16, Whh16, bih, bhh, x, out);
}

// Round 3
// 582.309 us; speedup vs baseline: 1.3604x; 1.3604x over previous
//
#include <hip/hip_runtime.h>
#include <hip/hip_bf16.h>

#define B_ 8
#define N_ 2048
#define D_ 256

using bf16 = __hip_bfloat16;
typedef short v8s __attribute__((ext_vector_type(8)));
typedef float v4f __attribute__((ext_vector_type(4)));

__device__ __forceinline__ v4f mfma16(v8s a, v8s b, v4f c) {
  return __builtin_amdgcn_mfma_f32_16x16x32_bf16(a, b, c, 0, 0, 0);
}
__device__ __forceinline__ v8s ldb8(const bf16* p) {
  return *reinterpret_cast<const v8s*>(p);
}
__device__ __forceinline__ unsigned short f2bu(float f) {
  bf16 b = __float2bfloat16(f);
  return *reinterpret_cast<unsigned short*>(&b);
}
__device__ __forceinline__ float fsigmoid(float x) { return 1.0f / (1.0f + __expf(-x)); }
__device__ __forceinline__ float ftanh(float x) {
  float ax = fabsf(x);
  float t = __expf(-2.0f * ax);
  float r = (1.0f - t) / (1.0f + t);
  return copysignf(r, x);
}

// ---------------- K0: f32 -> bf16 cast (vector x4) ----------------
__global__ __launch_bounds__(256) void k_cvt(const float* __restrict__ src,
                                             bf16* __restrict__ dst, int n4) {
  int i = blockIdx.x * 256 + threadIdx.x;
  if (i >= n4) return;
  float4 v = reinterpret_cast<const float4*>(src)[i];
  ushort4 o;
  o.x = f2bu(v.x); o.y = f2bu(v.y); o.z = f2bu(v.z); o.w = f2bu(v.w);
  reinterpret_cast<ushort4*>(dst)[i] = o;
}

// ---------------- K0b: x_topic cast + fused reciprocal row norms ----------------
// one wave (64 lanes x float4) covers exactly one 256-elem row
__global__ __launch_bounds__(256) void k_cvtn(const float* __restrict__ xt,
                                              bf16* __restrict__ dst,
                                              float* __restrict__ rnorm) {
  int i = blockIdx.x * 256 + threadIdx.x;          // 1048576 float4 slots
  int lane = threadIdx.x & 63;
  float4 v = reinterpret_cast<const float4*>(xt)[i];
  ushort4 o;
  o.x = f2bu(v.x); o.y = f2bu(v.y); o.z = f2bu(v.z); o.w = f2bu(v.w);
  reinterpret_cast<ushort4*>(dst)[i] = o;
  float s = v.x * v.x + v.y * v.y + v.z * v.z + v.w * v.w;
#pragma unroll
  for (int off = 32; off > 0; off >>= 1) s += __shfl_xor(s, off);
  if (lane == 0) rnorm[i >> 6] = 1.0f / fmaxf(sqrtf(s), 1e-8f);
}

// ---------------- K1: pack adj int32 -> 64-col bitmask words ----------------
// word g covers cols [g*64, g*64+64) of row g/(N/64); bit k = col g*64+k
__global__ __launch_bounds__(256) void k_pack(const int* __restrict__ adj,
                                              unsigned long long* __restrict__ adjp) {
  int wid = (blockIdx.x * 256 + threadIdx.x) >> 6;   // 16384 waves
  int lane = threadIdx.x & 63;
  const int G = B_ * N_ * (N_ / 64);                 // 524288 groups
#pragma unroll 4
  for (int g = wid; g < G; g += 16384) {
    int v = adj[(size_t)g * 64 + lane];
    unsigned long long m = __ballot(v > 0);
    if (lane == 0) adjp[g] = m;
  }
}

// ---------------- K2: W[d][h] (f32) -> Wt[h][d] (bf16, K-major) ----------------
__global__ __launch_bounds__(256) void k_twt(const float* __restrict__ W,
                                             bf16* __restrict__ Wt) {
  int idx = blockIdx.x * 256 + threadIdx.x;        // 65536
  int d = idx >> 8, h = idx & 255;
  Wt[h * 256 + d] = __float2bfloat16(W[idx]);
}

// ---------------- K3: WhT[b][h][m] = sum_d Wt[h][d] * x16[b][m][d] ----------------
__global__ __launch_bounds__(256) void k_wht(const bf16* __restrict__ x,
                                             const bf16* __restrict__ Wt,
                                             bf16* __restrict__ WhT) {
  int wid = blockIdx.x * 4 + (threadIdx.x >> 6);   // 4096 waves
  int lane = threadIdx.x & 63, lr = lane & 15, quad = lane >> 4;
  int b = wid >> 9;
  int rem = wid & 511;
  int h0 = (rem >> 5) << 4;                        // 16 h-tiles
  int m0 = (rem & 31) << 6;                        // 32 m-strips of 64

  v8s a[8];
  const bf16* arow = Wt + (size_t)(h0 + lr) * D_ + quad * 8;
#pragma unroll
  for (int ks = 0; ks < 8; ks++) a[ks] = ldb8(arow + ks * 32);

  const bf16* xb = x + (size_t)b * N_ * D_;
#pragma unroll
  for (int mt = 0; mt < 4; mt++) {
    v4f acc = {0.f, 0.f, 0.f, 0.f};
    const bf16* brow = xb + (size_t)(m0 + mt * 16 + lr) * D_ + quad * 8;
#pragma unroll
    for (int ks = 0; ks < 8; ks++) acc = mfma16(a[ks], ldb8(brow + ks * 32), acc);
    bf16* o = WhT + ((size_t)b * D_ + h0 + quad * 4) * N_ + m0 + mt * 16 + lr;
#pragma unroll
    for (int r = 0; r < 4; r++) o[(size_t)r * N_] = __float2bfloat16(acc[r]);
  }
}

// ---------------- K4: fused masked-cosine softmax attention v2 ----------------
// block = 32 Q-rows (2 MFMA tiles per wave, shared K/WhT fragments);
// 4 waves split the m-range 4-way; partial O/lsum combined via LDS ds_add_f32.
// XCD swizzle: batch = blockIdx.x & 7 (each XCD keeps one batch L2-resident).
__global__ __launch_bounds__(256, 2) void k_attn(const bf16* __restrict__ xt,
                                                 const unsigned long long* __restrict__ adjp,
                                                 const bf16* __restrict__ WhT,
                                                 const float* __restrict__ rnorm,
                                                 bf16* __restrict__ gout) {
  __shared__ __align__(16) bf16 pbuf[2][4][2][16][32]; // [dbuf][wave][tile][row][col] 16 KB
  __shared__ float oacc[32][256];                      // 32 KB
  __shared__ float lsacc[32];

  int w = threadIdx.x >> 6;
  int lane = threadIdx.x & 63, lr = lane & 15, quad = lane >> 4;
  int b  = blockIdx.x & 7;
  int n0 = (blockIdx.x >> 3) << 5;                     // 64 pair-tiles, step 32

  for (int i = threadIdx.x; i < 32 * 256; i += 256) (&oacc[0][0])[i] = 0.f;
  if (threadIdx.x < 32) lsacc[threadIdx.x] = 0.f;
  __syncthreads();

  const bf16* xtb = xt + (size_t)b * N_ * D_;
  const bf16* whb = WhT + (size_t)b * D_ * N_;
  const float* rnb = rnorm + b * N_;
  const unsigned long long* adjb = adjp + (size_t)b * N_ * (N_ / 64);

  // Q fragments for both 16-row tiles, held in registers
  v8s q0[8], q1[8];
  const bf16* q0r = xtb + (size_t)(n0 + lr) * D_ + quad * 8;
  const bf16* q1r = q0r + 16 * D_;
#pragma unroll
  for (int ks = 0; ks < 8; ks++) { q0[ks] = ldb8(q0r + ks * 32); q1[ks] = ldb8(q1r + ks * 32); }

  float rn0[4], rn1[4];
#pragma unroll
  for (int r = 0; r < 4; r++) {
    rn0[r] = rnb[n0 + quad * 4 + r];
    rn1[r] = rnb[n0 + 16 + quad * 4 + r];
  }

  v4f o0[16], o1[16];
#pragma unroll
  for (int t = 0; t < 16; t++) { o0[t] = (v4f){0,0,0,0}; o1[t] = (v4f){0,0,0,0}; }
  float ls0[4] = {0,0,0,0}, ls1[4] = {0,0,0,0};

#pragma unroll 1
  for (int ii = 0; ii < 16; ii++) {
    int mi = w * 16 + ii;                            // this wave's m-quarter
    int m0 = mi * 32;
    v4f s00 = {0,0,0,0}, s01 = {0,0,0,0}, s10 = {0,0,0,0}, s11 = {0,0,0,0};
    const bf16* k0r = xtb + (size_t)(m0 + lr) * D_ + quad * 8;
    const bf16* k1r = k0r + 16 * D_;
#pragma unroll
    for (int ks = 0; ks < 8; ks++) {
      v8s kf0 = ldb8(k0r + ks * 32);
      v8s kf1 = ldb8(k1r + ks * 32);
      s00 = mfma16(q0[ks], kf0, s00);
      s10 = mfma16(q1[ks], kf0, s10);
      s01 = mfma16(q0[ks], kf1, s01);
      s11 = mfma16(q1[ks], kf1, s11);
    }
    float rm0 = rnb[m0 + lr];
    float rm1 = rnb[m0 + 16 + lr];
    int widx = mi >> 1, wsh = (mi & 1) * 32;
    int bsel = ii & 1;
#pragma unroll
    for (int r = 0; r < 4; r++) {
      unsigned int mw0 = (unsigned int)(adjb[(size_t)(n0 + quad * 4 + r) * 32 + widx] >> wsh);
      unsigned int mw1 = (unsigned int)(adjb[(size_t)(n0 + 16 + quad * 4 + r) * 32 + widx] >> wsh);
      float p00 = ((mw0 >> lr) & 1u)        ? __expf(s00[r] * rn0[r] * rm0) : 0.f;
      float p01 = ((mw0 >> (lr + 16)) & 1u) ? __expf(s01[r] * rn0[r] * rm1) : 0.f;
      float p10 = ((mw1 >> lr) & 1u)        ? __expf(s10[r] * rn1[r] * rm0) : 0.f;
      float p11 = ((mw1 >> (lr + 16)) & 1u) ? __expf(s11[r] * rn1[r] * rm1) : 0.f;
      ls0[r] += p00 + p01;
      ls1[r] += p10 + p11;
      pbuf[bsel][w][0][quad * 4 + r][lr]      = __float2bfloat16(p00);
      pbuf[bsel][w][0][quad * 4 + r][lr + 16] = __float2bfloat16(p01);
      pbuf[bsel][w][1][quad * 4 + r][lr]      = __float2bfloat16(p10);
      pbuf[bsel][w][1][quad * 4 + r][lr + 16] = __float2bfloat16(p11);
    }
    v8s pa0 = *reinterpret_cast<const v8s*>(&pbuf[bsel][w][0][lr][quad * 8]);
    v8s pa1 = *reinterpret_cast<const v8s*>(&pbuf[bsel][w][1][lr][quad * 8]);
#pragma unroll
    for (int ht = 0; ht < 16; ht++) {
      v8s wf = ldb8(whb + (size_t)(ht * 16 + lr) * N_ + m0 + quad * 8);
      o0[ht] = mfma16(pa0, wf, o0[ht]);
      o1[ht] = mfma16(pa1, wf, o1[ht]);
    }
  }

  // combine partial row-sums (within-quad shfl reduce, then one LDS add)
#pragma unroll
  for (int r = 0; r < 4; r++) {
    float t0 = ls0[r], t1 = ls1[r];
    t0 += __shfl_xor(t0, 1); t0 += __shfl_xor(t0, 2);
    t0 += __shfl_xor(t0, 4); t0 += __shfl_xor(t0, 8);
    t1 += __shfl_xor(t1, 1); t1 += __shfl_xor(t1, 2);
    t1 += __shfl_xor(t1, 4); t1 += __shfl_xor(t1, 8);
    if (lr == 0) {
      atomicAdd(&lsacc[quad * 4 + r], t0);
      atomicAdd(&lsacc[16 + quad * 4 + r], t1);
    }
  }
  // combine partial O tiles
#pragma unroll
  for (int ht = 0; ht < 16; ht++) {
#pragma unroll
    for (int r = 0; r < 4; r++) {
      atomicAdd(&oacc[quad * 4 + r][ht * 16 + lr], o0[ht][r]);
      atomicAdd(&oacc[16 + quad * 4 + r][ht * 16 + lr], o1[ht][r]);
    }
  }
  __syncthreads();

  // normalize + coalesced bf16 store
  bf16* ob = gout + ((size_t)b * N_ + n0) * D_;
#pragma unroll 4
  for (int k = 0; k < 32; k++) {
    float inv = 1.0f / lsacc[k];
    ob[(size_t)k * D_ + threadIdx.x] = __float2bfloat16(oacc[k][threadIdx.x] * inv);
  }
}

// ---------------- K5: fused GRU cell (f32 out) ----------------
__global__ __launch_bounds__(256) void k_gru(const bf16* __restrict__ gout,
                                             const bf16* __restrict__ x16,
                                             const bf16* __restrict__ Wih,
                                             const bf16* __restrict__ Whh,
                                             const float* __restrict__ bih,
                                             const float* __restrict__ bhh,
                                             const float* __restrict__ x32,
                                             float* __restrict__ out) {
  int wid = blockIdx.x * 4 + (threadIdx.x >> 6);   // 4096 waves
  int lane = threadIdx.x & 63, lr = lane & 15, quad = lane >> 4;
  int rs = wid >> 4;                               // 256 row-strips of 64
  int col0 = (wid & 15) << 4;                      // 16 col-tiles
  int row0 = rs << 6;
  int col = col0 + lr;

  float bi[3], bh[3];
#pragma unroll
  for (int g = 0; g < 3; g++) {
    bi[g] = bih[g * 256 + col];
    bh[g] = bhh[g * 256 + col];
  }
  v4f aI[3][4], aH[3][4];
#pragma unroll
  for (int g = 0; g < 3; g++)
#pragma unroll
    for (int rt = 0; rt < 4; rt++) {
      aI[g][rt] = (v4f){0,0,0,0};
      aH[g][rt] = (v4f){0,0,0,0};
    }

#pragma unroll 2
  for (int ks = 0; ks < 8; ks++) {
    int k0 = ks * 32 + quad * 8;
    v8s wI[3], wH[3];
#pragma unroll
    for (int g = 0; g < 3; g++) {
      wI[g] = ldb8(Wih + (size_t)(g * 256 + col0 + lr) * 256 + k0);
      wH[g] = ldb8(Whh + (size_t)(g * 256 + col0 + lr) * 256 + k0);
    }
#pragma unroll
    for (int rt = 0; rt < 4; rt++) {
      v8s aG = ldb8(gout + (size_t)(row0 + rt * 16 + lr) * 256 + k0);
      v8s aX = ldb8(x16 + (size_t)(row0 + rt * 16 + lr) * 256 + k0);
#pragma unroll
      for (int g = 0; g < 3; g++) {
        aI[g][rt] = mfma16(aG, wI[g], aI[g][rt]);
        aH[g][rt] = mfma16(aX, wH[g], aH[g][rt]);
      }
    }
  }

#pragma unroll
  for (int rt = 0; rt < 4; rt++) {
    int rowb = row0 + rt * 16 + quad * 4;
#pragma unroll
    for (int r = 0; r < 4; r++) {
      float ir  = aI[0][rt][r] + bi[0];
      float iz  = aI[1][rt][r] + bi[1];
      float in_ = aI[2][rt][r] + bi[2];
      float hr  = aH[0][rt][r] + bh[0];
      float hz  = aH[1][rt][r] + bh[1];
      float hn  = aH[2][rt][r] + bh[2];
      float rg = fsigmoid(ir + hr);
      float zg = fsigmoid(iz + hz);
      float ng = ftanh(in_ + rg * hn);
      float hv = x32[(size_t)(rowb + r) * 256 + col];
      out[(size_t)(rowb + r) * 256 + col] = (1.0f - zg) * ng + zg * hv;
    }
  }
}

extern "C" void kernel_launch(void* const* d_in, const int* in_sizes, int n_in,
                              void* d_out, int out_size, void* d_ws, size_t ws_size,
                              hipStream_t stream) {
  const int*   adj = (const int*)d_in[0];
  const float* x   = (const float*)d_in[1];
  const float* xt  = (const float*)d_in[2];
  const float* W   = (const float*)d_in[3];
  const float* Wih = (const float*)d_in[4];
  const float* Whh = (const float*)d_in[5];
  const float* bih = (const float*)d_in[6];
  const float* bhh = (const float*)d_in[7];
  float* out = (float*)d_out;

  char* ws = (char*)d_ws;
  bf16*  xb16   = (bf16*)(ws);                               //  8 MiB
  bf16*  xtb16  = (bf16*)(ws + (8u << 20));                  //  8 MiB
  bf16*  gob    = (bf16*)(ws + (16u << 20));                 //  8 MiB
  bf16*  WhT    = (bf16*)(ws + (24u << 20));                 //  8 MiB
  bf16*  Wt     = (bf16*)(ws + (32u << 20));                 // 128 KiB
  bf16*  Wih16  = (bf16*)(ws + (32u << 20) + (128u << 10));  // 384 KiB
  bf16*  Whh16  = (bf16*)(ws + (32u << 20) + (512u << 10));  // 384 KiB
  float* rnorm  = (float*)(ws + (32u << 20) + (896u << 10)); //  64 KiB
  unsigned long long* adjp =
      (unsigned long long*)(ws + (32u << 20) + (960u << 10));//   4 MiB

  const int nBND4 = B_ * N_ * D_ / 4;                        // 1048576
  k_pack<<<4096, 256, 0, stream>>>(adj, adjp);
  k_cvt<<<nBND4 / 256, 256, 0, stream>>>(x, xb16, nBND4);
  k_cvtn<<<nBND4 / 256, 256, 0, stream>>>(xt, xtb16, rnorm);
  k_cvt<<<192, 256, 0, stream>>>(Wih, Wih16, 49152);
  k_cvt<<<192, 256, 0, stream>>>(Whh, Whh16, 49152);
  k_twt<<<256, 256, 0, stream>>>(W, Wt);
  k_wht<<<1024, 256, 0, stream>>>(xb16, Wt, WhT);
  k_attn<<<512, 256, 0, stream>>>(xtb16, adjp, WhT, rnorm, gob);
  k_gru<<<1024, 256, 0, stream>>>(gob, xb16, Wih16, Whh16, bih, bhh, x, out);
}

// Round 4
// 400.548 us; speedup vs baseline: 1.9777x; 1.4538x over previous
//
#include <hip/hip_runtime.h>
#include <hip/hip_bf16.h>

#define B_ 8
#define N_ 2048
#define D_ 256

using bf16 = __hip_bfloat16;
typedef short v8s __attribute__((ext_vector_type(8)));
typedef float v4f __attribute__((ext_vector_type(4)));
typedef unsigned int u32;
typedef unsigned long long u64;

__device__ __forceinline__ v4f mfma16(v8s a, v8s b, v4f c) {
  return __builtin_amdgcn_mfma_f32_16x16x32_bf16(a, b, c, 0, 0, 0);
}
__device__ __forceinline__ v8s ldb8(const bf16* p) {
  return *reinterpret_cast<const v8s*>(p);
}
__device__ __forceinline__ void glds16(const void* g, void* l) {
  __builtin_amdgcn_global_load_lds((const __attribute__((address_space(1))) u32*)g,
                                   (__attribute__((address_space(3))) u32*)l, 16, 0, 0);
}
__device__ __forceinline__ unsigned short f2bu(float f) {
  bf16 b = __float2bfloat16(f);
  return *reinterpret_cast<unsigned short*>(&b);
}
__device__ __forceinline__ float lo16(u32 u) { union {u32 i; float f;} v; v.i = u << 16; return v.f; }
__device__ __forceinline__ float hi16(u32 u) { union {u32 i; float f;} v; v.i = u & 0xffff0000u; return v.f; }
__device__ __forceinline__ u32 pack2(float a, float b) {
  return (u32)f2bu(a) | ((u32)f2bu(b) << 16);
}
__device__ __forceinline__ float fsigmoid(float x) { return 1.0f / (1.0f + __expf(-x)); }
__device__ __forceinline__ float ftanh(float x) {
  float ax = fabsf(x);
  float t = __expf(-2.0f * ax);
  float r = (1.0f - t) / (1.0f + t);
  return copysignf(r, x);
}

// ---------------- K0: f32 -> bf16 cast (vector x4) ----------------
__global__ __launch_bounds__(256) void k_cvt(const float* __restrict__ src,
                                             bf16* __restrict__ dst, int n4) {
  int i = blockIdx.x * 256 + threadIdx.x;
  if (i >= n4) return;
  float4 v = reinterpret_cast<const float4*>(src)[i];
  ushort4 o;
  o.x = f2bu(v.x); o.y = f2bu(v.y); o.z = f2bu(v.z); o.w = f2bu(v.w);
  reinterpret_cast<ushort4*>(dst)[i] = o;
}

// ---------------- K0b: x_topic cast + fused reciprocal row norms ----------------
__global__ __launch_bounds__(256) void k_cvtn(const float* __restrict__ xt,
                                              bf16* __restrict__ dst,
                                              float* __restrict__ rnorm) {
  int i = blockIdx.x * 256 + threadIdx.x;          // 1048576 float4 slots
  int lane = threadIdx.x & 63;
  float4 v = reinterpret_cast<const float4*>(xt)[i];
  ushort4 o;
  o.x = f2bu(v.x); o.y = f2bu(v.y); o.z = f2bu(v.z); o.w = f2bu(v.w);
  reinterpret_cast<ushort4*>(dst)[i] = o;
  float s = v.x * v.x + v.y * v.y + v.z * v.z + v.w * v.w;
#pragma unroll
  for (int off = 32; off > 0; off >>= 1) s += __shfl_xor(s, off);
  if (lane == 0) rnorm[i >> 6] = 1.0f / fmaxf(sqrtf(s), 1e-8f);
}

// ---------------- K1: pack adj int32 -> 64-col bitmask words ----------------
__global__ __launch_bounds__(256) void k_pack(const int* __restrict__ adj,
                                              u64* __restrict__ adjp) {
  int wid = (blockIdx.x * 256 + threadIdx.x) >> 6;   // 16384 waves
  int lane = threadIdx.x & 63;
  const int G = B_ * N_ * (N_ / 64);                 // 524288 groups
#pragma unroll 4
  for (int g = wid; g < G; g += 16384) {
    int v = adj[(size_t)g * 64 + lane];
    u64 m = __ballot(v > 0);
    if (lane == 0) adjp[g] = m;
  }
}

// ---------------- K2: W[d][h] (f32) -> Wt[h][d] (bf16, K-major) ----------------
__global__ __launch_bounds__(256) void k_twt(const float* __restrict__ W,
                                             bf16* __restrict__ Wt) {
  int idx = blockIdx.x * 256 + threadIdx.x;        // 65536
  int d = idx >> 8, h = idx & 255;
  Wt[h * 256 + d] = __float2bfloat16(W[idx]);
}

// ---------------- K3: WhT[b][h][m] = sum_d Wt[h][d] * x16[b][m][d] ----------------
__global__ __launch_bounds__(256) void k_wht(const bf16* __restrict__ x,
                                             const bf16* __restrict__ Wt,
                                             bf16* __restrict__ WhT) {
  int wid = blockIdx.x * 4 + (threadIdx.x >> 6);   // 4096 waves
  int lane = threadIdx.x & 63, lr = lane & 15, quad = lane >> 4;
  int b = wid >> 9;
  int rem = wid & 511;
  int h0 = (rem >> 5) << 4;                        // 16 h-tiles
  int m0 = (rem & 31) << 6;                        // 32 m-strips of 64

  v8s a[8];
  const bf16* arow = Wt + (size_t)(h0 + lr) * D_ + quad * 8;
#pragma unroll
  for (int ks = 0; ks < 8; ks++) a[ks] = ldb8(arow + ks * 32);

  const bf16* xb = x + (size_t)b * N_ * D_;
#pragma unroll
  for (int mt = 0; mt < 4; mt++) {
    v4f acc = {0.f, 0.f, 0.f, 0.f};
    const bf16* brow = xb + (size_t)(m0 + mt * 16 + lr) * D_ + quad * 8;
#pragma unroll
    for (int ks = 0; ks < 8; ks++) acc = mfma16(a[ks], ldb8(brow + ks * 32), acc);
    bf16* o = WhT + ((size_t)b * D_ + h0 + quad * 4) * N_ + m0 + mt * 16 + lr;
#pragma unroll
    for (int r = 0; r < 4; r++) o[(size_t)r * N_] = __float2bfloat16(acc[r]);
  }
}

// ---------------- K4: fused masked-cosine softmax attention v3 ----------------
// block = 64 Q-rows (wave w owns 16), ALL waves share each 32-wide m-tile.
// K-tile + WhT-tile staged in LDS via global_load_lds (dbuf, 1 barrier/iter).
// K-tile LDS layout XOR-swizzled (granule ^ (row&7)) for bank-conflict-free
// ds_read_b128 at 512B row stride. m-range split x2 across blocks; partial
// bf16 O + f32 row-sums written to global, combined by k_comb.
__global__ __launch_bounds__(256, 2) void k_attn(const bf16* __restrict__ xt,
                                                 const u64* __restrict__ adjp,
                                                 const bf16* __restrict__ WhT,
                                                 const float* __restrict__ rnorm,
                                                 bf16* __restrict__ po,
                                                 float* __restrict__ pls) {
  __shared__ __align__(16) bf16 xts[2][32][256];   // 32 KB (swizzled rows)
  __shared__ __align__(16) bf16 whs[2][256][32];   // 32 KB ([h][k])
  __shared__ __align__(16) bf16 pbuf[4][16][32];   //  4 KB (per-wave P)
  __shared__ float rns[1024];                      //  4 KB

  const int tid = threadIdx.x;
  const int w = tid >> 6, lane = tid & 63, lr = lane & 15, quad = lane >> 4;
  const int b = blockIdx.x & 7;                    // XCD-resident batch
  const int nt = (blockIdx.x >> 3) & 31;
  const int mh = blockIdx.x >> 8;
  const int n0w = nt * 64 + w * 16;
  const int mbase = mh * 1024;

  const bf16* xtb = xt + (size_t)b * N_ * D_;
  const bf16* whb = WhT + (size_t)b * D_ * N_;
  const float* rnb = rnorm + b * N_;
  const u64* adjb = adjp + (size_t)b * N_ * 32;

  // stage this half's rnorm into LDS
  ((float4*)rns)[tid] = ((const float4*)(rnb + mbase))[tid];

  // Q fragments (A-layout) in registers for the whole kernel
  v8s q[8];
  {
    const bf16* qrow = xtb + (size_t)(n0w + lr) * D_ + quad * 8;
#pragma unroll
    for (int kt = 0; kt < 8; kt++) q[kt] = ldb8(qrow + kt * 32);
  }
  float rn[4];
#pragma unroll
  for (int r = 0; r < 4; r++) rn[r] = rnb[n0w + quad * 4 + r];

  auto stage = [&](int d, int m0) {
    // K-tile: rows m0..m0+32 of xt (512 B each), XOR-swizzled granules
    const char* gx = (const char*)(xtb + (size_t)m0 * D_);
    char* lx = (char*)(&xts[d][0][0]) + w * 4096;
#pragma unroll
    for (int j = 0; j < 4; j++) {
      int m = w * 8 + j * 2 + (lane >> 5);
      int gg = (lane & 31) ^ (m & 7);
      glds16(gx + (size_t)m * 512 + gg * 16, lx + j * 1024);
    }
    // WhT-tile: 256 h-rows x 32 m-cols -> whs[h][k] (64 B rows)
    char* lw = (char*)(&whs[d][0][0]) + w * 4096;
#pragma unroll
    for (int j = 0; j < 4; j++) {
      int h = w * 64 + j * 16 + (lane >> 2);
      const char* gw = (const char*)(whb + (size_t)h * N_ + m0) + (lane & 3) * 16;
      glds16(gw, lw + j * 1024);
    }
  };

  u64 mk[4];
  auto ldadj = [&](int ii) {
    int c = mh * 16 + (ii >> 1);
#pragma unroll
    for (int r = 0; r < 4; r++) mk[r] = adjb[(size_t)(n0w + quad * 4 + r) * 32 + c];
  };

  v4f o[16];
#pragma unroll
  for (int t = 0; t < 16; t++) o[t] = (v4f){0, 0, 0, 0};
  float lsum[4] = {0, 0, 0, 0};

  stage(0, mbase);
  ldadj(0);

#pragma unroll 1
  for (int ii = 0; ii < 32; ii++) {
    const int d = ii & 1;
    const int m0 = mbase + ii * 32;
    __syncthreads();                       // drains stage(ii) (issued last iter)
    if (ii + 1 < 32) stage(1 - d, m0 + 32);

    // QK: S(16x32) from LDS B-frags (swizzled)
    v4f s0 = {0, 0, 0, 0}, s1 = {0, 0, 0, 0};
#pragma unroll
    for (int kt = 0; kt < 8; kt++) {
      int g = ((kt * 4 + quad) ^ (lr & 7)) * 8;
      v8s b0 = ldb8(&xts[d][lr][g]);
      v8s b1 = ldb8(&xts[d][lr + 16][g]);
      s0 = mfma16(q[kt], b0, s0);
      s1 = mfma16(q[kt], b1, s1);
    }

    float rm0 = rns[ii * 32 + lr];
    float rm1 = rns[ii * 32 + 16 + lr];
    const int wsh = (ii & 1) * 32;
    u32 mw[4];
#pragma unroll
    for (int r = 0; r < 4; r++) mw[r] = (u32)(mk[r] >> wsh);
    if (ii + 1 < 32) ldadj(ii + 1);        // prefetch next adj words

#pragma unroll
    for (int r = 0; r < 4; r++) {
      float p0 = ((mw[r] >> lr) & 1u)        ? __expf(s0[r] * rn[r] * rm0) : 0.f;
      float p1 = ((mw[r] >> (lr + 16)) & 1u) ? __expf(s1[r] * rn[r] * rm1) : 0.f;
      lsum[r] += p0 + p1;
      pbuf[w][quad * 4 + r][lr]      = __float2bfloat16(p0);
      pbuf[w][quad * 4 + r][lr + 16] = __float2bfloat16(p1);
    }
    v8s pa = ldb8(&pbuf[w][lr][quad * 8]);
#pragma unroll
    for (int ht = 0; ht < 16; ht++) {
      v8s wf = ldb8(&whs[d][ht * 16 + lr][quad * 8]);
      o[ht] = mfma16(pa, wf, o[ht]);
    }
  }

  // partial row-sums (f32) + partial O (bf16) to global
#pragma unroll
  for (int r = 0; r < 4; r++) {
    float t = lsum[r];
    t += __shfl_xor(t, 1); t += __shfl_xor(t, 2);
    t += __shfl_xor(t, 4); t += __shfl_xor(t, 8);
    lsum[r] = t;
  }
  float* plsb = pls + (size_t)mh * (B_ * N_) + (size_t)b * N_;
  if (lr == 0) {
#pragma unroll
    for (int r = 0; r < 4; r++) plsb[n0w + quad * 4 + r] = lsum[r];
  }
  bf16* pob = po + (size_t)mh * ((size_t)B_ * N_ * D_) +
              ((size_t)b * N_ + n0w + quad * 4) * D_ + lr;
#pragma unroll
  for (int r = 0; r < 4; r++) {
#pragma unroll
    for (int ht = 0; ht < 16; ht++) {
      pob[(size_t)r * D_ + ht * 16] = __float2bfloat16(o[ht][r]);
    }
  }
}

// ---------------- K4b: combine two m-halves + normalize -> gout bf16 ----------------
__global__ __launch_bounds__(256) void k_comb(const bf16* __restrict__ po,
                                              const float* __restrict__ pls,
                                              bf16* __restrict__ gout) {
  int idx = blockIdx.x * 256 + threadIdx.x;        // 524288 chunks of 8 bf16
  int row = idx >> 5;                               // 32 chunks per 256-col row
  float inv = 1.0f / (pls[row] + pls[B_ * N_ + row]);
  const uint4* p0 = (const uint4*)po;
  const uint4* p1 = (const uint4*)(po + (size_t)B_ * N_ * D_);
  uint4 a = p0[idx], c = p1[idx];
  uint4 o;
  o.x = pack2((lo16(a.x) + lo16(c.x)) * inv, (hi16(a.x) + hi16(c.x)) * inv);
  o.y = pack2((lo16(a.y) + lo16(c.y)) * inv, (hi16(a.y) + hi16(c.y)) * inv);
  o.z = pack2((lo16(a.z) + lo16(c.z)) * inv, (hi16(a.z) + hi16(c.z)) * inv);
  o.w = pack2((lo16(a.w) + lo16(c.w)) * inv, (hi16(a.w) + hi16(c.w)) * inv);
  reinterpret_cast<uint4*>(gout)[idx] = o;
}

// ---------------- K5: fused GRU cell (f32 out) ----------------
__global__ __launch_bounds__(256) void k_gru(const bf16* __restrict__ gout,
                                             const bf16* __restrict__ x16,
                                             const bf16* __restrict__ Wih,
                                             const bf16* __restrict__ Whh,
                                             const float* __restrict__ bih,
                                             const float* __restrict__ bhh,
                                             const float* __restrict__ x32,
                                             float* __restrict__ out) {
  int wid = blockIdx.x * 4 + (threadIdx.x >> 6);   // 4096 waves
  int lane = threadIdx.x & 63, lr = lane & 15, quad = lane >> 4;
  int rs = wid >> 4;                               // 256 row-strips of 64
  int col0 = (wid & 15) << 4;                      // 16 col-tiles
  int row0 = rs << 6;
  int col = col0 + lr;

  float bi[3], bh[3];
#pragma unroll
  for (int g = 0; g < 3; g++) {
    bi[g] = bih[g * 256 + col];
    bh[g] = bhh[g * 256 + col];
  }
  v4f aI[3][4], aH[3][4];
#pragma unroll
  for (int g = 0; g < 3; g++)
#pragma unroll
    for (int rt = 0; rt < 4; rt++) {
      aI[g][rt] = (v4f){0, 0, 0, 0};
      aH[g][rt] = (v4f){0, 0, 0, 0};
    }

#pragma unroll 2
  for (int ks = 0; ks < 8; ks++) {
    int k0 = ks * 32 + quad * 8;
    v8s wI[3], wH[3];
#pragma unroll
    for (int g = 0; g < 3; g++) {
      wI[g] = ldb8(Wih + (size_t)(g * 256 + col0 + lr) * 256 + k0);
      wH[g] = ldb8(Whh + (size_t)(g * 256 + col0 + lr) * 256 + k0);
    }
#pragma unroll
    for (int rt = 0; rt < 4; rt++) {
      v8s aG = ldb8(gout + (size_t)(row0 + rt * 16 + lr) * 256 + k0);
      v8s aX = ldb8(x16 + (size_t)(row0 + rt * 16 + lr) * 256 + k0);
#pragma unroll
      for (int g = 0; g < 3; g++) {
        aI[g][rt] = mfma16(aG, wI[g], aI[g][rt]);
        aH[g][rt] = mfma16(aX, wH[g], aH[g][rt]);
      }
    }
  }

#pragma unroll
  for (int rt = 0; rt < 4; rt++) {
    int rowb = row0 + rt * 16 + quad * 4;
#pragma unroll
    for (int r = 0; r < 4; r++) {
      float ir  = aI[0][rt][r] + bi[0];
      float iz  = aI[1][rt][r] + bi[1];
      float in_ = aI[2][rt][r] + bi[2];
      float hr  = aH[0][rt][r] + bh[0];
      float hz  = aH[1][rt][r] + bh[1];
      float hn  = aH[2][rt][r] + bh[2];
      float rg = fsigmoid(ir + hr);
      float zg = fsigmoid(iz + hz);
      float ng = ftanh(in_ + rg * hn);
      float hv = x32[(size_t)(rowb + r) * 256 + col];
      out[(size_t)(rowb + r) * 256 + col] = (1.0f - zg) * ng + zg * hv;
    }
  }
}

extern "C" void kernel_launch(void* const* d_in, const int* in_sizes, int n_in,
                              void* d_out, int out_size, void* d_ws, size_t ws_size,
                              hipStream_t stream) {
  const int*   adj = (const int*)d_in[0];
  const float* x   = (const float*)d_in[1];
  const float* xt  = (const float*)d_in[2];
  const float* W   = (const float*)d_in[3];
  const float* Wih = (const float*)d_in[4];
  const float* Whh = (const float*)d_in[5];
  const float* bih = (const float*)d_in[6];
  const float* bhh = (const float*)d_in[7];
  float* out = (float*)d_out;

  char* ws = (char*)d_ws;
  bf16*  xb16   = (bf16*)(ws);                               //  8 MiB
  bf16*  xtb16  = (bf16*)(ws + (8u << 20));                  //  8 MiB
  bf16*  gob    = (bf16*)(ws + (16u << 20));                 //  8 MiB
  bf16*  WhT    = (bf16*)(ws + (24u << 20));                 //  8 MiB
  bf16*  Wt     = (bf16*)(ws + (32u << 20));                 // 128 KiB
  bf16*  Wih16  = (bf16*)(ws + (32u << 20) + (128u << 10));  // 384 KiB
  bf16*  Whh16  = (bf16*)(ws + (32u << 20) + (512u << 10));  // 384 KiB
  float* rnorm  = (float*)(ws + (32u << 20) + (896u << 10)); //  64 KiB
  u64*   adjp   = (u64*)  (ws + (32u << 20) + (960u << 10)); //   4 MiB
  bf16*  po     = (bf16*) (ws + (40u << 20));                //  16 MiB (2 halves)
  float* pls    = (float*)(ws + (56u << 20));                // 128 KiB

  const int nBND4 = B_ * N_ * D_ / 4;                        // 1048576
  k_pack<<<4096, 256, 0, stream>>>(adj, adjp);
  k_cvt<<<nBND4 / 256, 256, 0, stream>>>(x, xb16, nBND4);
  k_cvtn<<<nBND4 / 256, 256, 0, stream>>>(xt, xtb16, rnorm);
  k_cvt<<<192, 256, 0, stream>>>(Wih, Wih16, 49152);
  k_cvt<<<192, 256, 0, stream>>>(Whh, Whh16, 49152);
  k_twt<<<256, 256, 0, stream>>>(W, Wt);
  k_wht<<<1024, 256, 0, stream>>>(xb16, Wt, WhT);
  k_attn<<<512, 256, 0, stream>>>(xtb16, adjp, WhT, rnorm, po, pls);
  k_comb<<<2048, 256, 0, stream>>>(po, pls, gob);
  k_gru<<<1024, 256, 0, stream>>>(gob, xb16, Wih16, Whh16, bih, bhh, x, out);
}